// Round 18
// baseline (147.687 us; speedup 1.0000x reference)
//
#include <hip/hip_runtime.h>
#include <hip/hip_fp16.h>

#define B 64
#define N 4096
#define M 128

constexpr int T   = 256;    // 4 waves; 64 KiB LDS -> 2 co-resident blocks/CU
constexpr int NWG = 1024;   // 64 batches x 16 channel-groups (8 ch each)

__device__ __forceinline__ float2 cadd(float2 a, float2 b){ return make_float2(a.x+b.x, a.y+b.y); }
__device__ __forceinline__ float2 csub(float2 a, float2 b){ return make_float2(a.x-b.x, a.y-b.y); }
__device__ __forceinline__ float2 cmul(float2 a, float2 b){ return make_float2(a.x*b.x - a.y*b.y, a.x*b.y + a.y*b.x); }
__device__ __forceinline__ float2 mulnegi(float2 a){ return make_float2(a.y, -a.x); }
__device__ __forceinline__ float2 muli(float2 a)  { return make_float2(-a.y, a.x); }
__device__ __forceinline__ float2 cis(float ang){ float s, c; __sincosf(ang, &s, &c); return make_float2(c, s); }
__device__ __forceinline__ float2 h2f(__half2 h){ return __half22float2(h); }
__device__ __forceinline__ __half2 f2h(float2 v){ return __floats2half2_rn(v.x, v.y); }

// W64^d = cis(-2*pi*d/64), d = 0..7  (literal table, no runtime sincos)
__device__ __constant__ const float W64R[8] = {
    1.0f, 0.995184726672197f, 0.980785280403230f, 0.956940335732209f,
    0.923879532511287f, 0.881921264348355f, 0.831469612302545f, 0.773010453362737f };
__device__ __constant__ const float W64I[8] = {
    0.0f, -0.098017140329561f, -0.195090322016128f, -0.290284677254462f,
    -0.382683432365090f, -0.471396736825998f, -0.555570233019602f, -0.634393284163645f };

// forward DFT8 in place (W8 = e^{-i pi/4}): t_out[k] = sum_c t_in[c] W8^{ck}
__device__ __forceinline__ void dft8(float2 t[8]) {
    float2 e0=cadd(t[0],t[4]), e1=csub(t[0],t[4]);
    float2 e2=cadd(t[2],t[6]), e3=csub(t[2],t[6]);
    float2 E0=cadd(e0,e2), E2=csub(e0,e2);
    float2 E1=cadd(e1,mulnegi(e3)), E3=cadd(e1,muli(e3));
    float2 o0=cadd(t[1],t[5]), o1=csub(t[1],t[5]);
    float2 o2=cadd(t[3],t[7]), o3=csub(t[3],t[7]);
    float2 O0=cadd(o0,o2), O2=csub(o0,o2);
    float2 O1=cadd(o1,mulnegi(o3)), O3=cadd(o1,muli(o3));
    const float C = 0.70710678118654752f;
    float2 w1O1 = make_float2(C*(O1.x+O1.y), C*(O1.y-O1.x));
    float2 w2O2 = mulnegi(O2);
    float2 w3O3 = make_float2(C*(O3.y-O3.x), -C*(O3.x+O3.y));
    t[0]=cadd(E0,O0);   t[4]=csub(E0,O0);
    t[1]=cadd(E1,w1O1); t[5]=csub(E1,w1O1);
    t[2]=cadd(E2,w2O2); t[6]=csub(E2,w2O2);
    t[3]=cadd(E3,w3O3); t[7]=csub(E3,w3O3);
}

// LDS half2 slot for (k1, n2, mc): XOR swizzle n2^(k1&7) => every phase <=2-way
__device__ __forceinline__ int lslot(int k1, int n2, int mc) {
    return (k1 << 8) | ((n2 ^ (k1 & 7)) << 2) | mc;
}

__global__ __launch_bounds__(T, 2)
void fft_one(const float* __restrict__ x, float* __restrict__ out) {
    extern __shared__ __half2 lz[];   // [k1][n2sw][mc] = 64*64*4 half2 = 64 KiB

    // bid%8 = b&7 -> all 16 channel-groups of a batch on one XCD (L2 line merge)
    const int bid = blockIdx.x;
    const int b   = ((bid >> 7) << 3) | (bid & 7);
    const int mcg = (bid >> 3) & 15;
    const int tid = threadIdx.x;
    const int mc  = tid & 3;        // packed channel pair within group (4 -> 8 ch)
    const int rp  = tid >> 2;       // phase A: n2 ; phase B: k1 ; unpack: r

    const float* xb = x + (size_t)b * N * M + mcg * 8 + mc * 2;

    __half2 pk[8][8];   // fp16-packed pass-1 intermediates (64 VGPRs, static idx)

    // ======== phase A: FFT64 over n1 of column n2=rp ========
    // pass 1: per column bb, load 8 rows, DFT8, pack. U_bb[d] = pk[bb][d]
    #pragma unroll
    for (int bb = 0; bb < 8; ++bb) {
        float2 t[8];
        #pragma unroll
        for (int a = 0; a < 8; ++a)
            t[a] = *(const float2*)(xb + (size_t)(64*(8*a+bb) + rp) * M);
        dft8(t);
        #pragma unroll
        for (int d = 0; d < 8; ++d) pk[bb][d] = f2h(t[d]);
    }
    // pass 2: X[8c+d] = DFT8_bb( W64^{bb*d} * U_bb[d] )[c], then global twiddle
    // W4096^{rp*(8c+d)} = (W4096^{8rp})^c * (W4096^{rp})^d, then LDS write.
    {
        const float2 ws = cis(-6.2831853071795864f * (float)rp / 4096.0f); // W4096^rp
        const float2 w8 = cis(-6.2831853071795864f * (float)rp / 512.0f);  // W4096^(8rp)
        float2 pd = make_float2(1.f, 0.f);
        #pragma unroll
        for (int d = 0; d < 8; ++d) {
            const float2 wd = make_float2(W64R[d], W64I[d]);
            float2 t[8];
            t[0] = h2f(pk[0][d]);
            float2 w = wd;
            #pragma unroll
            for (int bb = 1; bb < 8; ++bb) {
                t[bb] = cmul(h2f(pk[bb][d]), w);
                w = cmul(w, wd);
            }
            dft8(t);
            float2 ac = pd;
            #pragma unroll
            for (int c = 0; c < 8; ++c) {
                lz[lslot(8*c+d, rp, mc)] = f2h(cmul(t[c], ac));
                ac = cmul(ac, w8);
            }
            pd = cmul(pd, ws);
        }
    }
    __syncthreads();

    // ======== phase B: FFT64 over n2 of own slice k1=rp ========
    #pragma unroll
    for (int bb = 0; bb < 8; ++bb) {
        float2 t[8];
        #pragma unroll
        for (int a = 0; a < 8; ++a)
            t[a] = h2f(lz[lslot(rp, 8*a+bb, mc)]);
        dft8(t);
        #pragma unroll
        for (int d = 0; d < 8; ++d) pk[bb][d] = f2h(t[d]);
    }
    #pragma unroll
    for (int d = 0; d < 8; ++d) {
        const float2 wd = make_float2(W64R[d], W64I[d]);
        float2 t[8];
        t[0] = h2f(pk[0][d]);
        float2 w = wd;
        #pragma unroll
        for (int bb = 1; bb < 8; ++bb) {
            t[bb] = cmul(h2f(pk[bb][d]), w);
            w = cmul(w, wd);
        }
        dft8(t);
        #pragma unroll
        for (int c = 0; c < 8; ++c)
            lz[lslot(rp, 8*c+d, mc)] = f2h(t[c]);   // Z[k2=8c+d], self-owned slice
    }
    __syncthreads();

    // ======== Hermitian unpack + coalesced stores (rows k = 64j + r) ========
    float* outRe = out + (size_t)b * N * M + mcg * 8 + mc * 2;
    float* outIm = outRe + (size_t)B * N * M;
    const int r = rp;
    #pragma unroll 4
    for (int j = 0; j < 64; ++j) {
        int k   = (j << 6) | r;
        int kk  = (N - k) & (N - 1);
        int k1p = kk & 63, k2p = kk >> 6;
        float2 Zk = h2f(lz[lslot(r,   j,   mc)]);
        float2 Zm = h2f(lz[lslot(k1p, k2p, mc)]);
        float2 re = make_float2(0.5f * (Zk.x + Zm.x), 0.5f * (Zk.y + Zm.y));
        float2 im = make_float2(0.5f * (Zk.y - Zm.y), 0.5f * (Zm.x - Zk.x));
        *(float2*)(outRe + (size_t)k * M) = re;
        *(float2*)(outIm + (size_t)k * M) = im;
    }
}

extern "C" void kernel_launch(void* const* d_in, const int* in_sizes, int n_in,
                              void* d_out, int out_size, void* d_ws, size_t ws_size,
                              hipStream_t stream) {
    const float* x = (const float*)d_in[0];
    float* out = (float*)d_out;
    const int lds_bytes = 64 * 64 * 4 * (int)sizeof(__half2);   // 65536
    hipFuncSetAttribute((const void*)fft_one,
                        hipFuncAttributeMaxDynamicSharedMemorySize, lds_bytes);
    fft_one<<<NWG, T, lds_bytes, stream>>>(x, out);
}